// Round 1
// baseline (231.534 us; speedup 1.0000x reference)
//
#include <hip/hip_runtime.h>
#include <stdint.h>

#define TB   256
#define TLEN 2048
#define NB   16
#define NCH  128
#define BN   (NB*NCH)   // 2048 rows
#define KP   6

// ---------------------------------------------------------------------------
// K0: transpose x[b][t][n] -> seqs[(b*NCH+n)][t]   (coalesced both sides)
// ---------------------------------------------------------------------------
__global__ __launch_bounds__(256) void k_transpose_in(const float* __restrict__ x,
                                                      float* __restrict__ seqs) {
  __shared__ float tile[64][65];
  int t0 = blockIdx.x * 64, n0 = blockIdx.y * 64, b = blockIdx.z;
  int tx = threadIdx.x & 63, ty = threadIdx.x >> 6;
#pragma unroll
  for (int tt = ty; tt < 64; tt += 4)
    tile[tt][tx] = x[(size_t)(b * TLEN + t0 + tt) * NCH + n0 + tx];
  __syncthreads();
#pragma unroll
  for (int nn = ty; nn < 64; nn += 4)
    seqs[(size_t)(b * NCH + n0 + nn) * TLEN + t0 + tx] = tile[tx][nn];
}

// ---------------------------------------------------------------------------
// K1: per-row 2048-pt complex FFT (radix-2 Stockham, LDS) + top-6 bins
// params[row*KP+r] = {P, base, cycles, 0}
// ---------------------------------------------------------------------------
__global__ __launch_bounds__(256) void k_fft_topk(const float* __restrict__ seqs,
                                                  const float* __restrict__ x,
                                                  int strided,
                                                  int4* __restrict__ params) {
  __shared__ float sm[8192];            // buf0: [0..2047]=re [2048..4095]=im
  __shared__ unsigned long long wmax[4]; // buf1: [4096..6143]=re [6144..8191]=im
  int row = blockIdx.x;
  int tid = threadIdx.x;

  float* xr = sm;        float* xi = sm + 2048;
  float* yr = sm + 4096; float* yi = sm + 6144;

  if (strided) {
    int b = row >> 7, n = row & 127;
    for (int i = tid; i < TLEN; i += TB) {
      xr[i] = x[(size_t)(b * TLEN + i) * NCH + n];
      xi[i] = 0.f;
    }
  } else {
    for (int i = tid; i < TLEN; i += TB) {
      xr[i] = seqs[(size_t)row * TLEN + i];
      xi[i] = 0.f;
    }
  }

  int ncur = 2048;
  for (int st = 0; st < 11; st++) {
    int m = ncur >> 1;
    int s = 1 << st;
    float ang0 = (float)(-6.283185307179586 / (double)ncur);
    __syncthreads();
    for (int i = tid; i < 1024; i += TB) {
      int q = i & (s - 1);
      int p = i >> st;
      float ar = xr[q + s * p],       ai = xi[q + s * p];
      float br = xr[q + s * (p + m)], bi = xi[q + s * (p + m)];
      yr[q + s * (2 * p)] = ar + br;
      yi[q + s * (2 * p)] = ai + bi;
      float dr = ar - br, di = ai - bi;
      float sn, cs;
      sincosf(ang0 * (float)p, &sn, &cs);
      yr[q + s * (2 * p + 1)] = dr * cs - di * sn;
      yi[q + s * (2 * p + 1)] = dr * sn + di * cs;
    }
    float* t;
    t = xr; xr = yr; yr = t;
    t = xi; xi = yi; yi = t;
    ncur >>= 1;
  }
  // 11 stages (odd) -> final result in buf1 (sm+4096 / sm+6144); buf0 is dead.
  __syncthreads();
  const float* resr = sm + 4096;
  const float* resi = sm + 6144;
  unsigned long long* keys = (unsigned long long*)sm;  // aliases dead buf0 re-half (8KB)
  for (int i = tid; i < 1024; i += TB) {
    int bin = i + 1;                       // bins 1..1024 (DC killed)
    float rr = resr[bin], ii = resi[bin];
    float m2 = rr * rr + ii * ii;
    // larger mag2 wins; tie -> smaller bin wins (lax.top_k semantics)
    keys[i] = ((unsigned long long)__float_as_uint(m2) << 32) |
              (unsigned)(0xFFFFFFFFu - (unsigned)bin);
  }
  __syncthreads();

  for (int r = 0; r < KP; r++) {
    unsigned long long best = 0ull;
    for (int i = tid; i < 1024; i += TB) {
      unsigned long long v = keys[i];
      best = v > best ? v : best;
    }
    for (int off = 32; off > 0; off >>= 1) {
      unsigned long long o = __shfl_down(best, off);
      best = o > best ? o : best;
    }
    if ((tid & 63) == 0) wmax[tid >> 6] = best;
    __syncthreads();
    if (tid == 0) {
      best = wmax[0];
      for (int w = 1; w < 4; w++) best = wmax[w] > best ? wmax[w] : best;
      int bin = (int)(0xFFFFFFFFu - (unsigned)(best & 0xFFFFFFFFull));
      keys[bin - 1] = 0ull;               // remove for next round
      int P = TLEN / bin; if (P < 1) P = 1;
      int cyc = TLEN / P;
      int base = TLEN - cyc * P;
      params[row * KP + r] = make_int4(P, base, cyc, 0);
    }
    __syncthreads();
  }
}

// ---------------------------------------------------------------------------
// K2: fold one (row,k) -> seg[(row*KP+k)][0:TLEN]  (zero-padded past P)
// ---------------------------------------------------------------------------
__global__ __launch_bounds__(256) void k_fold(const float* __restrict__ seqs,
                                              const int4* __restrict__ params,
                                              float* __restrict__ seg) {
  int kk = blockIdx.x, row = blockIdx.y;
  int tid = threadIdx.x;
  int4 pr = params[row * KP + kk];
  int P = pr.x, base = pr.y, cyc = pr.z;
  float inv = 1.0f / (float)cyc;
  const float* src = seqs + (size_t)row * TLEN + base;
  __shared__ float acc[TLEN];

  if (P <= 16) {
    // register path: thread t owns cycles t, t+256, ... ; contiguous P-chunks
    float a[16];
#pragma unroll
    for (int p = 0; p < 16; p++) a[p] = 0.f;
    for (int c = tid; c < cyc; c += TB) {
      const float* s2 = src + c * P;
#pragma unroll
      for (int p = 0; p < 16; p++)
        if (p < P) a[p] += s2[p];
    }
    if (tid < P) acc[tid] = 0.f;
    __syncthreads();
#pragma unroll
    for (int p = 0; p < 16; p++)
      if (p < P) {
        float v = a[p];
        for (int off = 32; off > 0; off >>= 1) v += __shfl_down(v, off);
        if ((tid & 63) == 0) atomicAdd(&acc[p], v);
      }
    __syncthreads();
  } else {
    for (int i = tid; i < P; i += TB) acc[i] = 0.f;
    __syncthreads();
    int take = cyc * P;
    unsigned magic = (unsigned)((0x100000000ULL + (unsigned)P - 1) / (unsigned)P);
    for (int idx = tid; idx < take; idx += TB) {
      float v = src[idx];
      unsigned q = __umulhi((unsigned)idx, magic);   // exact: idx<2^11, e<P
      int p = idx - (int)(q * (unsigned)P);
      atomicAdd(&acc[p], v);                         // ds_add_f32
    }
    __syncthreads();
  }

  float* dst = seg + ((size_t)row * KP + kk) * TLEN;
  for (int p = tid; p < TLEN; p += TB) dst[p] = (p < P) ? acc[p] * inv : 0.f;
}

// ---------------------------------------------------------------------------
// K3: transpose seg[(b*NCH+n)*KP+k][p] -> out[((b*KP+k)*TLEN+p)*NCH+n]
// ---------------------------------------------------------------------------
__global__ __launch_bounds__(256) void k_transpose_out(const float* __restrict__ seg,
                                                       float* __restrict__ out) {
  __shared__ float tile[64][65];
  int p0 = blockIdx.x * 64, n0 = blockIdx.y * 64, bk = blockIdx.z;
  int b = bk / KP, k = bk - b * KP;
  int tx = threadIdx.x & 63, ty = threadIdx.x >> 6;
#pragma unroll
  for (int nn = ty; nn < 64; nn += 4)
    tile[nn][tx] = seg[((size_t)(b * NCH + n0 + nn) * KP + k) * TLEN + p0 + tx];
  __syncthreads();
#pragma unroll
  for (int pp = ty; pp < 64; pp += 4)
    out[((size_t)bk * TLEN + p0 + pp) * NCH + n0 + tx] = tile[tx][pp];
}

// ---------------------------------------------------------------------------
// Fallback: direct fold into out (divergent gather), if ws can't hold seg
// ---------------------------------------------------------------------------
__global__ __launch_bounds__(256) void k_fold_direct(const float* __restrict__ seqs,
                                                     const float* __restrict__ x,
                                                     int strided,
                                                     const int4* __restrict__ params,
                                                     float* __restrict__ out) {
  int tid = threadIdx.x;
  int n = tid & 127, dp = tid >> 7;
  int p = blockIdx.x * 2 + dp;
  int k = blockIdx.y, b = blockIdx.z;
  int row = b * NCH + n;
  int4 pr = params[row * KP + k];
  float v = 0.f;
  if (p < pr.x) {
    float s = 0.f;
    if (strided) {
      for (int c = 0; c < pr.z; c++)
        s += x[(size_t)(b * TLEN + pr.y + c * pr.x + p) * NCH + n];
    } else {
      const float* sr = seqs + (size_t)row * TLEN + pr.y + p;
      for (int c = 0; c < pr.z; c++) s += sr[(size_t)c * pr.x];
    }
    v = s / (float)pr.z;
  }
  out[((size_t)(b * KP + k) * TLEN + p) * NCH + n] = v;
}

// ---------------------------------------------------------------------------
extern "C" void kernel_launch(void* const* d_in, const int* in_sizes, int n_in,
                              void* d_out, int out_size, void* d_ws, size_t ws_size,
                              hipStream_t stream) {
  const float* x = (const float*)d_in[0];
  float* out = (float*)d_out;
  char* ws = (char*)d_ws;

  const size_t seqs_bytes   = (size_t)BN * TLEN * 4;        // 16.8 MB
  const size_t params_bytes = (size_t)BN * KP * 16;         // 196 KB
  const size_t seg_bytes    = (size_t)BN * KP * TLEN * 4;   // 100.7 MB

  bool have_seqs = ws_size >= seqs_bytes + params_bytes;
  bool have_seg  = ws_size >= seqs_bytes + params_bytes + seg_bytes;

  float* seqs = nullptr;
  int4* params;
  float* seg = nullptr;
  if (have_seqs) {
    seqs   = (float*)ws;
    params = (int4*)(ws + seqs_bytes);
    seg    = (float*)(ws + seqs_bytes + params_bytes);
  } else {
    params = (int4*)ws;   // params alone (196 KB) assumed to fit
  }

  if (have_seqs) {
    k_transpose_in<<<dim3(TLEN / 64, NCH / 64, NB), 256, 0, stream>>>(x, seqs);
    k_fft_topk<<<dim3(BN), 256, 0, stream>>>(seqs, x, 0, params);
  } else {
    k_fft_topk<<<dim3(BN), 256, 0, stream>>>(x, x, 1, params);
  }

  if (have_seg) {
    k_fold<<<dim3(KP, BN), 256, 0, stream>>>(seqs, params, seg);
    k_transpose_out<<<dim3(TLEN / 64, NCH / 64, NB * KP), 256, 0, stream>>>(seg, out);
  } else {
    k_fold_direct<<<dim3(TLEN / 2, KP, NB), 256, 0, stream>>>(
        have_seqs ? seqs : x, x, have_seqs ? 0 : 1, params, out);
  }
}

// Round 2
// 215.110 us; speedup vs baseline: 1.0764x; 1.0764x over previous
//
#include <hip/hip_runtime.h>
#include <stdint.h>

#define TB   256
#define TLEN 2048
#define NB   16
#define NCH  128
#define BN   (NB*NCH)   // 2048 rows
#define KP   6

typedef unsigned long long u64;

// ---------------------------------------------------------------------------
// K0: zero-fill out (100.7 MB) — out must be fully written every call
// ---------------------------------------------------------------------------
__global__ __launch_bounds__(256) void k_fill0(float4* __restrict__ out, int n4) {
  int i = blockIdx.x * blockDim.x + threadIdx.x;
  int stride = gridDim.x * blockDim.x;
  float4 z = make_float4(0.f, 0.f, 0.f, 0.f);
  for (; i < n4; i += stride) out[i] = z;
}

// ---------------------------------------------------------------------------
// K1: transpose x[b][t][n] -> seqs[(b*NCH+n)][t]
// ---------------------------------------------------------------------------
__global__ __launch_bounds__(256) void k_transpose_in(const float* __restrict__ x,
                                                      float* __restrict__ seqs) {
  __shared__ float tile[64][65];
  int t0 = blockIdx.x * 64, n0 = blockIdx.y * 64, b = blockIdx.z;
  int tx = threadIdx.x & 63, ty = threadIdx.x >> 6;
#pragma unroll
  for (int tt = ty; tt < 64; tt += 4)
    tile[tt][tx] = x[(size_t)(b * TLEN + t0 + tt) * NCH + n0 + tx];
  __syncthreads();
#pragma unroll
  for (int nn = ty; nn < 64; nn += 4)
    seqs[(size_t)(b * NCH + n0 + nn) * TLEN + t0 + tx] = tile[tx][nn];
}

// ---------------------------------------------------------------------------
// K2: two-for-one real FFT (rows 2r, 2r+1 as re/im of one complex 2048 FFT)
// + twiddle table in LDS + top-6 bins per row.
// params[row*KP+r] = {P, base, cycles, 0}
// ---------------------------------------------------------------------------
__global__ __launch_bounds__(256) void k_fft_topk(const float* __restrict__ seqs,
                                                  int4* __restrict__ params) {
  __shared__ float2 bufA[2048];   // 16 KB; dead after FFT -> aliased as keys[2048]
  __shared__ float2 bufB[2048];   // 16 KB; holds final spectrum (11 stages = odd)
  __shared__ float2 tw[1024];     // 8 KB twiddles exp(-2*pi*i*j/2048)
  __shared__ u64 wmax[4];
  int tid = threadIdx.x;
  int r0 = blockIdx.x * 2;

  for (int t = tid; t < TLEN; t += TB) {
    float vr = seqs[(size_t)r0 * TLEN + t];
    float vi = seqs[(size_t)(r0 + 1) * TLEN + t];
    bufA[t] = make_float2(vr, vi);
  }
  const float c0 = -6.283185307179586f / 2048.0f;
  for (int j = tid; j < 1024; j += TB) {
    float sn, cs;
    sincosf(c0 * (float)j, &sn, &cs);
    tw[j] = make_float2(cs, sn);
  }

  float2* xb = bufA;
  float2* yb = bufB;
  for (int st = 0; st < 11; st++) {
    __syncthreads();
    int s = 1 << st;
#pragma unroll 1
    for (int i = tid; i < 1024; i += TB) {
      int q = i & (s - 1);
      int p = i >> st;
      float2 a = xb[i];          // q + s*p == i
      float2 b = xb[i + 1024];   // q + s*(p+m), s*m == 1024 for all stages
      float2 w = tw[p << st];
      int o = q + (p << (st + 1));
      yb[o] = make_float2(a.x + b.x, a.y + b.y);
      float dx = a.x - b.x, dy = a.y - b.y;
      yb[o + s] = make_float2(dx * w.x - dy * w.y, dx * w.y + dy * w.x);
    }
    float2* t2 = xb; xb = yb; yb = t2;
  }
  __syncthreads();
  // result in xb (== bufB); bufA + tw are dead
  const float2* Z = xb;
  u64* keys = (u64*)bufA;  // [0..1023]=row r0, [1024..2047]=row r0+1
  for (int i = tid; i < 1024; i += TB) {
    int kb = i + 1;                      // bins 1..1024 (DC excluded)
    float2 zk = Z[kb];
    float2 zc = Z[2048 - kb];
    float ax = zk.x + zc.x, ay = zk.y - zc.y;   // 2*X[kb]
    float bx = zk.x - zc.x, by = zk.y + zc.y;   // 2i*Y[kb]
    float m2a = ax * ax + ay * ay;              // 4*|X|^2 — constant scale, order-safe
    float m2b = bx * bx + by * by;
    keys[i]        = ((u64)__float_as_uint(m2a) << 32) | (unsigned)(0xFFFFFFFFu - (unsigned)kb);
    keys[1024 + i] = ((u64)__float_as_uint(m2b) << 32) | (unsigned)(0xFFFFFFFFu - (unsigned)kb);
  }
  __syncthreads();

  for (int rw = 0; rw < 2; rw++) {
    u64* kbase = keys + rw * 1024;
    for (int r = 0; r < KP; r++) {
      u64 best = 0ull;
      for (int i = tid; i < 1024; i += TB) {
        u64 v = kbase[i];
        best = v > best ? v : best;
      }
      for (int off = 32; off > 0; off >>= 1) {
        u64 o = __shfl_down(best, off);
        best = o > best ? o : best;
      }
      if ((tid & 63) == 0) wmax[tid >> 6] = best;
      __syncthreads();
      if (tid == 0) {
        best = wmax[0];
        for (int w = 1; w < 4; w++) best = wmax[w] > best ? wmax[w] : best;
        int bin = (int)(0xFFFFFFFFu - (unsigned)(best & 0xFFFFFFFFull));
        if (bin < 1 || bin > 1024) bin = 1;     // safety (unreachable for real data)
        kbase[bin - 1] = 0ull;
        int P = TLEN / bin;
        int cyc = TLEN / P;
        int base = TLEN - cyc * P;
        params[(r0 + rw) * KP + r] = make_int4(P, base, cyc, 0);
      }
      __syncthreads();
    }
  }
}

// ---------------------------------------------------------------------------
// K3: per-row fold for all 6 k's; scatter-store only p < P directly into out.
// out layout: out[((b*KP+k)*TLEN+p)*NCH + n], row = b*NCH+n
// ---------------------------------------------------------------------------
__global__ __launch_bounds__(256) void k_fold_row(const float* __restrict__ seqs,
                                                  const int4* __restrict__ params,
                                                  float* __restrict__ out) {
  __shared__ float srow[TLEN];   // 8 KB
  __shared__ float acc[TLEN];    // 8 KB
  int row = blockIdx.x;
  int b = row >> 7, n = row & 127;
  int tid = threadIdx.x;
  for (int t = tid; t < TLEN; t += TB)
    srow[t] = seqs[(size_t)row * TLEN + t];

  for (int k = 0; k < KP; k++) {
    int4 pr = params[row * KP + k];
    int P = pr.x, base = pr.y, cyc = pr.z;
    float inv = 1.0f / (float)cyc;
    __syncthreads();   // srow ready (k=0); acc free of prior readers (k>0)

    if (P <= 16) {
      // register path: thread t owns cycles t, t+256, ...; conflict-light
      float a[16];
#pragma unroll
      for (int p = 0; p < 16; p++) a[p] = 0.f;
      for (int c = tid; c < cyc; c += TB) {
        int o = base + c * P;
#pragma unroll
        for (int p = 0; p < 16; p++)
          if (p < P) a[p] += srow[o + p];
      }
      if (tid < P) acc[tid] = 0.f;
      __syncthreads();
#pragma unroll
      for (int p = 0; p < 16; p++)
        if (p < P) {
          float v = a[p];
          for (int off = 32; off > 0; off >>= 1) v += __shfl_down(v, off);
          if ((tid & 63) == 0) atomicAdd(&acc[p], v);
        }
      __syncthreads();
    } else {
      for (int i = tid; i < P; i += TB) acc[i] = 0.f;
      __syncthreads();
      int take = cyc * P;
      unsigned magic = (unsigned)((0x100000000ULL + (unsigned)P - 1) / (unsigned)P);
      for (int idx = tid; idx < take; idx += TB) {
        unsigned q = __umulhi((unsigned)idx, magic);  // exact for all P here
        int p = idx - (int)(q * (unsigned)P);
        atomicAdd(&acc[p], srow[base + idx]);         // ds_add_f32
      }
      __syncthreads();
    }

    float* dst = out + (size_t)(b * KP + k) * TLEN * NCH + n;
    for (int p = tid; p < P; p += TB)
      dst[(size_t)p * NCH] = acc[p] * inv;            // sparse scatter, ~E[P]=15/row
  }
}

// ---------------------------------------------------------------------------
extern "C" void kernel_launch(void* const* d_in, const int* in_sizes, int n_in,
                              void* d_out, int out_size, void* d_ws, size_t ws_size,
                              hipStream_t stream) {
  const float* x = (const float*)d_in[0];
  float* out = (float*)d_out;
  char* ws = (char*)d_ws;

  const size_t seqs_bytes = (size_t)BN * TLEN * 4;   // 16.8 MB
  float* seqs = (float*)ws;
  int4* params = (int4*)(ws + seqs_bytes);           // 196 KB

  k_fill0<<<8192, 256, 0, stream>>>((float4*)out, out_size / 4);
  k_transpose_in<<<dim3(TLEN / 64, NCH / 64, NB), 256, 0, stream>>>(x, seqs);
  k_fft_topk<<<dim3(BN / 2), 256, 0, stream>>>(seqs, params);
  k_fold_row<<<dim3(BN), 256, 0, stream>>>(seqs, params, out);
}

// Round 3
// 178.623 us; speedup vs baseline: 1.2962x; 1.2043x over previous
//
#include <hip/hip_runtime.h>
#include <stdint.h>

#define TB   256
#define TLEN 2048
#define NB   16
#define NCH  128
#define BN   (NB*NCH)   // 2048 rows
#define KP   6

typedef unsigned long long u64;

// ---------------------------------------------------------------------------
// K0: zero-fill out (100.7 MB) — out must be fully written every call
// ---------------------------------------------------------------------------
__global__ __launch_bounds__(256) void k_fill0(float4* __restrict__ out, int n4) {
  int i = blockIdx.x * blockDim.x + threadIdx.x;
  int stride = gridDim.x * blockDim.x;
  float4 z = make_float4(0.f, 0.f, 0.f, 0.f);
  for (; i < n4; i += stride) out[i] = z;
}

// ---------------------------------------------------------------------------
// K1: transpose x[b][t][n] -> seqs[(b*NCH+n)][t]
// ---------------------------------------------------------------------------
__global__ __launch_bounds__(256) void k_transpose_in(const float* __restrict__ x,
                                                      float* __restrict__ seqs) {
  __shared__ float tile[64][65];
  int t0 = blockIdx.x * 64, n0 = blockIdx.y * 64, b = blockIdx.z;
  int tx = threadIdx.x & 63, ty = threadIdx.x >> 6;
#pragma unroll
  for (int tt = ty; tt < 64; tt += 4)
    tile[tt][tx] = x[(size_t)(b * TLEN + t0 + tt) * NCH + n0 + tx];
  __syncthreads();
#pragma unroll
  for (int nn = ty; nn < 64; nn += 4)
    seqs[(size_t)(b * NCH + n0 + nn) * TLEN + t0 + tx] = tile[tx][nn];
}

// ---------------------------------------------------------------------------
// K2: two-for-one real FFT (rows 2r, 2r+1 as re/im of one complex 2048 FFT)
// + twiddle table in LDS + top-6 bins per row.  512 threads: 8 waves/block,
// 4 blocks/CU (40KB LDS) = 32 waves/CU full occupancy.
// params[row*KP+r] = {P, base, cycles, 0}
// ---------------------------------------------------------------------------
#define FT 512
__global__ __launch_bounds__(FT) void k_fft_topk(const float* __restrict__ seqs,
                                                 int4* __restrict__ params) {
  __shared__ float2 bufA[2048];   // 16 KB; dead after FFT -> aliased as keys[2048]
  __shared__ float2 bufB[2048];   // 16 KB; holds final spectrum (11 stages = odd)
  __shared__ float2 tw[1024];     // 8 KB twiddles exp(-2*pi*i*j/2048)
  __shared__ u64 wmax[FT / 64];
  int tid = threadIdx.x;
  int r0 = blockIdx.x * 2;

  for (int t = tid; t < TLEN; t += FT) {
    float vr = seqs[(size_t)r0 * TLEN + t];
    float vi = seqs[(size_t)(r0 + 1) * TLEN + t];
    bufA[t] = make_float2(vr, vi);
  }
  const float c0 = -6.283185307179586f / 2048.0f;
  for (int j = tid; j < 1024; j += FT) {
    float sn, cs;
    sincosf(c0 * (float)j, &sn, &cs);
    tw[j] = make_float2(cs, sn);
  }

  float2* xb = bufA;
  float2* yb = bufB;
  for (int st = 0; st < 11; st++) {
    __syncthreads();
    int s = 1 << st;
#pragma unroll
    for (int ii = 0; ii < 1024 / FT; ii++) {
      int i = tid + ii * FT;
      int q = i & (s - 1);
      int p = i >> st;
      float2 a = xb[i];          // q + s*p == i
      float2 b = xb[i + 1024];   // q + s*(p+m), s*m == 1024 for all stages
      float2 w = tw[p << st];
      int o = q + (p << (st + 1));
      yb[o] = make_float2(a.x + b.x, a.y + b.y);
      float dx = a.x - b.x, dy = a.y - b.y;
      yb[o + s] = make_float2(dx * w.x - dy * w.y, dx * w.y + dy * w.x);
    }
    float2* t2 = xb; xb = yb; yb = t2;
  }
  __syncthreads();
  // result in xb (== bufB); bufA + tw are dead
  const float2* Z = xb;
  u64* keys = (u64*)bufA;  // [0..1023]=row r0, [1024..2047]=row r0+1
  for (int i = tid; i < 1024; i += FT) {
    int kb = i + 1;                      // bins 1..1024 (DC excluded)
    float2 zk = Z[kb];
    float2 zc = Z[2048 - kb];
    float ax = zk.x + zc.x, ay = zk.y - zc.y;   // 2*X[kb]
    float bx = zk.x - zc.x, by = zk.y + zc.y;   // 2i*Y[kb]
    float m2a = ax * ax + ay * ay;              // 4*|X|^2 — const scale, order-safe
    float m2b = bx * bx + by * by;
    keys[i]        = ((u64)__float_as_uint(m2a) << 32) | (unsigned)(0xFFFFFFFFu - (unsigned)kb);
    keys[1024 + i] = ((u64)__float_as_uint(m2b) << 32) | (unsigned)(0xFFFFFFFFu - (unsigned)kb);
  }
  __syncthreads();

  for (int rw = 0; rw < 2; rw++) {
    u64* kbase = keys + rw * 1024;
    for (int r = 0; r < KP; r++) {
      u64 best = 0ull;
      for (int i = tid; i < 1024; i += FT) {
        u64 v = kbase[i];
        best = v > best ? v : best;
      }
      for (int off = 32; off > 0; off >>= 1) {
        u64 o = __shfl_down(best, off);
        best = o > best ? o : best;
      }
      if ((tid & 63) == 0) wmax[tid >> 6] = best;
      __syncthreads();
      if (tid == 0) {
        best = wmax[0];
        for (int w = 1; w < FT / 64; w++) best = wmax[w] > best ? wmax[w] : best;
        int bin = (int)(0xFFFFFFFFu - (unsigned)(best & 0xFFFFFFFFull));
        if (bin < 1 || bin > 1024) bin = 1;     // safety
        kbase[bin - 1] = 0ull;
        int P = TLEN / bin;
        int cyc = TLEN / P;
        int base = TLEN - cyc * P;
        params[(r0 + rw) * KP + r] = make_int4(P, base, cyc, 0);
      }
      __syncthreads();
    }
  }
}

// ---------------------------------------------------------------------------
// K3: per-row fold, conflict-free & atomic-free.
// P>=64: phase-per-thread, contiguous-lane LDS reads, register accumulate.
// P<64 : lane i -> (ci=i/P, pi=i%P); wave reads srow[base+chunk+lane]
//        (contiguous), shuffle-doubling-tree reduce over same-phase lanes,
//        <=4P tiny LDS atomics to merge 4 waves.
// out layout: out[((b*KP+k)*TLEN+p)*NCH + n], row = b*NCH+n
// ---------------------------------------------------------------------------
__global__ __launch_bounds__(256) void k_fold_row(const float* __restrict__ seqs,
                                                  const int4* __restrict__ params,
                                                  float* __restrict__ out) {
  __shared__ float srow[TLEN];   // 8 KB
  __shared__ float acc[64];
  int row = blockIdx.x;
  int b = row >> 7, n = row & 127;
  int tid = threadIdx.x, lane = tid & 63, wv = tid >> 6;

  const float4* s4 = (const float4*)(seqs + (size_t)row * TLEN);
  float4* r4 = (float4*)srow;
  for (int i = tid; i < TLEN / 4; i += TB) r4[i] = s4[i];
  __syncthreads();

  for (int k = 0; k < KP; k++) {
    int4 pr = params[row * KP + k];
    int P = pr.x, base = pr.y, cyc = pr.z;
    float inv = 1.0f / (float)cyc;
    float* dst = out + (size_t)(b * KP + k) * TLEN * NCH + n;

    if (P >= 64) {
      for (int p0 = 0; p0 < P; p0 += TB) {
        int p = p0 + tid;
        if (p < P) {
          const float* sp = srow + base + p;
          float s = 0.f;
          for (int c = 0; c < cyc; c++) s += sp[c * P];   // lanes contiguous
          dst[(size_t)p * NCH] = s * inv;
        }
      }
    } else {
      int wc = 64 / P;        // cycles per wave per chunk
      int u = wc * P;         // active lanes per wave
      int ci = lane / P;
      int pi = lane - ci * P;
      float v = 0.f;
      if (lane < u) {
        for (int c0 = wv * wc; c0 < cyc; c0 += 4 * wc) {
          int c = c0 + ci;
          if (c < cyc) v += srow[base + c0 * P + lane];  // contiguous lanes
        }
      }
      for (int s = P; s < u; s <<= 1) {
        float o = __shfl_down(v, s);
        if (lane + s < u) v += o;
      }
      if (tid < 64) acc[tid] = 0.f;
      __syncthreads();
      if (lane < P) atomicAdd(&acc[pi], v);   // <= 4 adds per address
      __syncthreads();
      if (tid < P) dst[(size_t)tid * NCH] = acc[tid] * inv;
      __syncthreads();   // acc must be fully consumed before next k zeroes it
    }
  }
}

// ---------------------------------------------------------------------------
extern "C" void kernel_launch(void* const* d_in, const int* in_sizes, int n_in,
                              void* d_out, int out_size, void* d_ws, size_t ws_size,
                              hipStream_t stream) {
  const float* x = (const float*)d_in[0];
  float* out = (float*)d_out;
  char* ws = (char*)d_ws;

  const size_t seqs_bytes = (size_t)BN * TLEN * 4;   // 16.8 MB
  float* seqs = (float*)ws;
  int4* params = (int4*)(ws + seqs_bytes);           // 196 KB

  k_fill0<<<8192, 256, 0, stream>>>((float4*)out, out_size / 4);
  k_transpose_in<<<dim3(TLEN / 64, NCH / 64, NB), 256, 0, stream>>>(x, seqs);
  k_fft_topk<<<dim3(BN / 2), FT, 0, stream>>>(seqs, params);
  k_fold_row<<<dim3(BN), 256, 0, stream>>>(seqs, params, out);
}

// Round 4
// 154.287 us; speedup vs baseline: 1.5007x; 1.1577x over previous
//
#include <hip/hip_runtime.h>
#include <stdint.h>

#define TB   256
#define TLEN 2048
#define NB   16
#define NCH  128
#define BN   (NB*NCH)   // 2048 rows
#define KP   6

typedef unsigned long long u64;

__device__ inline float2 cmul(float2 a, float2 b) {
  return make_float2(a.x * b.x - a.y * b.y, a.x * b.y + a.y * b.x);
}

// ---------------------------------------------------------------------------
// K0: zero-fill out (100.7 MB)
// ---------------------------------------------------------------------------
__global__ __launch_bounds__(256) void k_fill0(float4* __restrict__ out, int n4) {
  int i = blockIdx.x * blockDim.x + threadIdx.x;
  int stride = gridDim.x * blockDim.x;
  float4 z = make_float4(0.f, 0.f, 0.f, 0.f);
  for (; i < n4; i += stride) out[i] = z;
}

// ---------------------------------------------------------------------------
// K1: transpose x[b][t][n] -> seqs[(b*NCH+n)][t]
// ---------------------------------------------------------------------------
__global__ __launch_bounds__(256) void k_transpose_in(const float* __restrict__ x,
                                                      float* __restrict__ seqs) {
  __shared__ float tile[64][65];
  int t0 = blockIdx.x * 64, n0 = blockIdx.y * 64, b = blockIdx.z;
  int tx = threadIdx.x & 63, ty = threadIdx.x >> 6;
#pragma unroll
  for (int tt = ty; tt < 64; tt += 4)
    tile[tt][tx] = x[(size_t)(b * TLEN + t0 + tt) * NCH + n0 + tx];
  __syncthreads();
#pragma unroll
  for (int nn = ty; nn < 64; nn += 4)
    seqs[(size_t)(b * NCH + n0 + nn) * TLEN + t0 + tx] = tile[tx][nn];
}

// ---------------------------------------------------------------------------
// K2: two-for-one real FFT via radix-4 Stockham (5 R4 stages + 1 R2 stage),
// padded LDS addressing (conflict-light), + top-6 bins per row.
// params[row*KP+r] = {P, base, cycles, 0}
// ---------------------------------------------------------------------------
#define PAD(o) ((o) + ((o) >> 4))
__global__ __launch_bounds__(256) void k_fft_topk(const float* __restrict__ seqs,
                                                  int4* __restrict__ params) {
  __shared__ float2 bufA[2176];   // 2048 + pad(128)  = 17.4 KB
  __shared__ float2 bufB[2176];   // 17.4 KB ; keys alias this after FFT
  __shared__ float2 tw[512];      // 4 KB: W_2048^j, j in [0,512)
  __shared__ u64 wmax[4];
  int tid = threadIdx.x;
  int lane = tid & 63, wv = tid >> 6;
  int r0 = blockIdx.x * 2;

  for (int t = tid; t < TLEN; t += TB) {
    float vr = seqs[(size_t)r0 * TLEN + t];
    float vi = seqs[(size_t)(r0 + 1) * TLEN + t];
    bufA[PAD(t)] = make_float2(vr, vi);
  }
  const float c0 = -6.283185307179586f / 2048.0f;
  for (int j = tid; j < 512; j += TB) {
    float sn, cs;
    sincosf(c0 * (float)j, &sn, &cs);
    tw[j] = make_float2(cs, sn);
  }

  float2* xb = bufA;
  float2* yb = bufB;
  // 5 radix-4 stages: s = 1,4,16,64,256  (fusion of radix-2 stages 0..9)
#pragma unroll 1
  for (int st2 = 0; st2 < 10; st2 += 2) {
    int s = 1 << st2;
    __syncthreads();
#pragma unroll
    for (int ii = 0; ii < 2; ii++) {
      int i = tid + ii * TB;            // [0,512)
      int q = i & (s - 1);
      int cb = i - q;                   // c*s = i & ~(s-1), < 512
      float2 A0 = xb[PAD(i)];
      float2 A1 = xb[PAD(i + 512)];
      float2 A2 = xb[PAD(i + 1024)];
      float2 A3 = xb[PAD(i + 1536)];
      float2 S02 = make_float2(A0.x + A2.x, A0.y + A2.y);
      float2 D02 = make_float2(A0.x - A2.x, A0.y - A2.y);
      float2 S13 = make_float2(A1.x + A3.x, A1.y + A3.y);
      float2 D13 = make_float2(A1.x - A3.x, A1.y - A3.y);
      float2 b0 = make_float2(S02.x + S13.x, S02.y + S13.y);
      float2 b1 = make_float2(D02.x + D13.y, D02.y - D13.x);  // D02 - i*D13
      float2 b2 = make_float2(S02.x - S13.x, S02.y - S13.y);
      float2 b3 = make_float2(D02.x - D13.y, D02.y + D13.x);  // D02 + i*D13
      float2 w1 = tw[cb];
      float2 w2 = make_float2(w1.x * w1.x - w1.y * w1.y, 2.f * w1.x * w1.y);
      float2 w3 = cmul(w1, w2);
      int o = q + 4 * cb;               // q + 4*s*c
      yb[PAD(o)]         = b0;
      yb[PAD(o + s)]     = cmul(w1, b1);
      yb[PAD(o + 2 * s)] = cmul(w2, b2);
      yb[PAD(o + 3 * s)] = cmul(w3, b3);
    }
    float2* t2 = xb; xb = yb; yb = t2;
  }
  // final radix-2 stage: s=1024, no twiddle
  __syncthreads();
#pragma unroll
  for (int ii = 0; ii < 4; ii++) {
    int i = tid + ii * TB;              // [0,1024)
    float2 a = xb[PAD(i)];
    float2 b = xb[PAD(i + 1024)];
    yb[PAD(i)]        = make_float2(a.x + b.x, a.y + b.y);
    yb[PAD(i + 1024)] = make_float2(a.x - b.x, a.y - b.y);
  }
  // 6 stages total: started in bufA -> result in bufA? 5 swaps after R4 stages
  // put result of stage k in the "other" buffer each time: after 5 R4 stages
  // data is in bufB (xb==bufB), final R2 writes yb==bufA.  Result: bufA.
  __syncthreads();
  const float2* Z = bufA;
  u64* keys = (u64*)bufB;  // [0..1023]=row r0, [1024..2047]=row r0+1
  for (int i = tid; i < 1024; i += TB) {
    int kb = i + 1;                      // bins 1..1024
    float2 zk = Z[PAD(kb)];
    float2 zc = Z[PAD(2048 - kb)];
    float ax = zk.x + zc.x, ay = zk.y - zc.y;   // 2*X[kb]
    float bx = zk.x - zc.x, by = zk.y + zc.y;   // 2i*Y[kb]
    float m2a = ax * ax + ay * ay;              // 4*|X|^2 — const scale, order-safe
    float m2b = bx * bx + by * by;
    keys[i]        = ((u64)__float_as_uint(m2a) << 32) | (unsigned)(0xFFFFFFFFu - (unsigned)kb);
    keys[1024 + i] = ((u64)__float_as_uint(m2b) << 32) | (unsigned)(0xFFFFFFFFu - (unsigned)kb);
  }
  __syncthreads();

  // top-6: waves 0-1 own row r0, waves 2-3 own row r0+1 (6 rounds)
  int rw = wv >> 1;                 // 0 or 1
  u64* kb2 = keys + rw * 1024;
  int t2 = tid & 127;               // index within the wave-pair
  for (int r = 0; r < KP; r++) {
    u64 best = 0ull;
    for (int i = t2; i < 1024; i += 128) {
      u64 v = kb2[i];
      best = v > best ? v : best;
    }
    for (int off = 32; off > 0; off >>= 1) {
      u64 o = __shfl_down(best, off);
      best = o > best ? o : best;
    }
    if (lane == 0) wmax[wv] = best;
    __syncthreads();
    if ((tid & 127) == 0) {
      u64 b0 = wmax[rw * 2], b1 = wmax[rw * 2 + 1];
      best = b0 > b1 ? b0 : b1;
      int bin = (int)(0xFFFFFFFFu - (unsigned)(best & 0xFFFFFFFFull));
      if (bin < 1 || bin > 1024) bin = 1;
      kb2[bin - 1] = 0ull;
      int P = TLEN / bin;
      int cyc = TLEN / P;
      int base = TLEN - cyc * P;
      params[(r0 + rw) * KP + r] = make_int4(P, base, cyc, 0);
    }
    __syncthreads();
  }
}

// ---------------------------------------------------------------------------
// K3: per-row fold; wave w handles k = w and w+4. No atomics, no barriers
// after the load. out[((b*KP+k)*TLEN+p)*NCH + n], row = b*NCH+n
// ---------------------------------------------------------------------------
__global__ __launch_bounds__(256) void k_fold_row(const float* __restrict__ seqs,
                                                  const int4* __restrict__ params,
                                                  float* __restrict__ out) {
  __shared__ float srow[TLEN];   // 8 KB
  int row = blockIdx.x;
  int b = row >> 7, n = row & 127;
  int tid = threadIdx.x, lane = tid & 63, wv = tid >> 6;

  const float4* s4 = (const float4*)(seqs + (size_t)row * TLEN);
  float4* r4 = (float4*)srow;
  for (int i = tid; i < TLEN / 4; i += TB) r4[i] = s4[i];
  __syncthreads();

  for (int k = wv; k < KP; k += 4) {
    int4 pr = params[row * KP + k];
    int P = pr.x, base = pr.y, cyc = pr.z;
    float inv = 1.0f / (float)cyc;
    float* dst = out + (size_t)(b * KP + k) * TLEN * NCH + n;

    if (P >= 64) {
      // cyc <= 32; lanes read contiguous addresses
      for (int p = lane; p < P; p += 64) {
        const float* sp = srow + base + p;
        float s = 0.f;
        for (int c = 0; c < cyc; c++) s += sp[c * P];
        dst[(size_t)p * NCH] = s * inv;
      }
    } else {
      int wc = 64 / P;        // cycles handled per chunk
      int u = wc * P;         // active lanes
      int ci = lane / P;
      float v = 0.f;
      if (lane < u) {
        for (int c0 = 0; c0 < cyc; c0 += wc) {
          int c = c0 + ci;
          if (c < cyc) v += srow[base + c0 * P + lane];  // contiguous lanes
        }
      }
      for (int s = P; s < u; s <<= 1) {
        float o = __shfl_down(v, s);
        if (lane + s < u) v += o;
      }
      if (lane < P) dst[(size_t)lane * NCH] = v * inv;
    }
  }
}

// ---------------------------------------------------------------------------
extern "C" void kernel_launch(void* const* d_in, const int* in_sizes, int n_in,
                              void* d_out, int out_size, void* d_ws, size_t ws_size,
                              hipStream_t stream) {
  const float* x = (const float*)d_in[0];
  float* out = (float*)d_out;
  char* ws = (char*)d_ws;

  const size_t seqs_bytes = (size_t)BN * TLEN * 4;   // 16.8 MB
  float* seqs = (float*)ws;
  int4* params = (int4*)(ws + seqs_bytes);           // 196 KB

  k_fill0<<<8192, 256, 0, stream>>>((float4*)out, out_size / 4);
  k_transpose_in<<<dim3(TLEN / 64, NCH / 64, NB), 256, 0, stream>>>(x, seqs);
  k_fft_topk<<<dim3(BN / 2), 256, 0, stream>>>(seqs, params);
  k_fold_row<<<dim3(BN), 256, 0, stream>>>(seqs, params, out);
}

// Round 5
// 145.103 us; speedup vs baseline: 1.5957x; 1.0633x over previous
//
#include <hip/hip_runtime.h>
#include <stdint.h>

#define TB   256
#define TLEN 2048
#define NB   16
#define NCH  128
#define BN   (NB*NCH)   // 2048 rows
#define KP   6

typedef unsigned long long u64;

__device__ inline float2 cmul(float2 a, float2 b) {
  return make_float2(a.x * b.x - a.y * b.y, a.x * b.y + a.y * b.x);
}
__device__ inline float2 cadd(float2 a, float2 b) { return make_float2(a.x + b.x, a.y + b.y); }
__device__ inline float2 csub(float2 a, float2 b) { return make_float2(a.x - b.x, a.y - b.y); }
__device__ inline float2 cmni(float2 a) { return make_float2(a.y, -a.x); }  // *(-i)

// ---------------------------------------------------------------------------
// K0: fused zero-fill(out) + transpose x[b][t][n] -> seqs[(b*NCH+n)][t]
// blocks [0,1024): transpose tiles; blocks [1024, ...): fill out
// ---------------------------------------------------------------------------
__global__ __launch_bounds__(256) void k_prep(const float* __restrict__ x,
                                              float* __restrict__ seqs,
                                              float4* __restrict__ out4, int n4) {
  int bid = blockIdx.x;
  if (bid < 1024) {
    __shared__ float tile[64][65];
    int tb = bid & 31, nb = (bid >> 5) & 1, b = bid >> 6;
    int t0 = tb * 64, n0 = nb * 64;
    int tx = threadIdx.x & 63, ty = threadIdx.x >> 6;
#pragma unroll
    for (int tt = ty; tt < 64; tt += 4)
      tile[tt][tx] = x[(size_t)(b * TLEN + t0 + tt) * NCH + n0 + tx];
    __syncthreads();
#pragma unroll
    for (int nn = ty; nn < 64; nn += 4)
      seqs[(size_t)(b * NCH + n0 + nn) * TLEN + t0 + tx] = tile[tx][nn];
  } else {
    int i = (bid - 1024) * 256 + threadIdx.x;
    if (i < n4) out4[i] = make_float4(0.f, 0.f, 0.f, 0.f);
  }
}

// ---------------------------------------------------------------------------
// K1: fused two-for-one real FFT (radix-8 x3 + radix-4, Stockham, padded LDS)
//     + top-6 per row + fold, written directly to out.
// ---------------------------------------------------------------------------
#define PAD(o) ((o) + ((o) >> 4))
#define C2 0.70710678118654752f

__global__ __launch_bounds__(256) void k_fft_fold(const float* __restrict__ seqs,
                                                  float* __restrict__ out) {
  __shared__ __align__(16) float2 bufA[2176];   // 17.4 KB; later aliased: srows[2][2048]
  __shared__ __align__(16) float2 bufB[2176];   // 17.4 KB; later aliased: keys u64[2048]
  __shared__ float2 tw[256];                    // 2 KB: W_2048^j, j<256
  __shared__ u64 wmax[4];
  __shared__ int4 prm[2][KP];
  int tid = threadIdx.x, lane = tid & 63, wv = tid >> 6;
  int r0 = blockIdx.x * 2;
  const float* row0 = seqs + (size_t)r0 * TLEN;

  // load rows 2r, 2r+1 as (re, im)
#pragma unroll
  for (int k = 0; k < 8; k++) {
    int t = tid + k * TB;
    bufA[PAD(t)] = make_float2(row0[t], row0[t + TLEN]);
  }
  {
    float sn, cs;
    sincosf((-6.283185307179586f / 2048.f) * (float)tid, &sn, &cs);
    tw[tid & 255] = make_float2(cs, sn);   // tid<256 so exact
  }

  float2* xb = bufA;
  float2* yb = bufB;
  // 3 radix-8 stages: s = 1, 8, 64 ; one butterfly per thread per stage
#pragma unroll
  for (int stage = 0; stage < 3; stage++) {
    int s = (stage == 0) ? 1 : (stage == 1) ? 8 : 64;
    __syncthreads();
    int i = tid;                 // butterfly id, [0,256)
    int q = i & (s - 1);
    int cb = i - q;              // c*s  (< 256)
    float2 A0 = xb[PAD(i)],        A1 = xb[PAD(i + 256)],
           A2 = xb[PAD(i + 512)],  A3 = xb[PAD(i + 768)],
           A4 = xb[PAD(i + 1024)], A5 = xb[PAD(i + 1280)],
           A6 = xb[PAD(i + 1536)], A7 = xb[PAD(i + 1792)];
    // DFT4 on evens (A0,A2,A4,A6)
    float2 s02 = cadd(A0, A4), d02 = csub(A0, A4);
    float2 s13 = cadd(A2, A6), d13 = csub(A2, A6);
    float2 E0 = cadd(s02, s13), E1 = cadd(d02, cmni(d13));
    float2 E2 = csub(s02, s13), E3 = csub(d02, cmni(d13));
    // DFT4 on odds (A1,A3,A5,A7)
    float2 t02 = cadd(A1, A5), e02 = csub(A1, A5);
    float2 t13 = cadd(A3, A7), e13 = csub(A3, A7);
    float2 O0 = cadd(t02, t13), O1 = cadd(e02, cmni(e13));
    float2 O2 = csub(t02, t13), O3 = csub(e02, cmni(e13));
    // T_j = w8^j * O_j ;  w8 = (1-i)/sqrt2
    float2 T0 = O0;
    float2 T1 = make_float2(C2 * (O1.x + O1.y), C2 * (O1.y - O1.x));
    float2 T2 = cmni(O2);
    float2 T3 = make_float2(C2 * (O3.y - O3.x), -C2 * (O3.x + O3.y));
    float2 B0 = cadd(E0, T0), B4 = csub(E0, T0);
    float2 B1 = cadd(E1, T1), B5 = csub(E1, T1);
    float2 B2 = cadd(E2, T2), B6 = csub(E2, T2);
    float2 B3 = cadd(E3, T3), B7 = csub(E3, T3);
    // twiddles w_j = (W_2048^{cb})^j
    float2 w1 = tw[cb];
    float2 w2 = cmul(w1, w1);
    float2 w3 = cmul(w2, w1);
    float2 w4 = cmul(w2, w2);
    float2 w5 = cmul(w4, w1);
    float2 w6 = cmul(w4, w2);
    float2 w7 = cmul(w4, w3);
    int o = q + 8 * cb;          // q + 8*s*c
    yb[PAD(o)]         = B0;
    yb[PAD(o + s)]     = cmul(w1, B1);
    yb[PAD(o + 2 * s)] = cmul(w2, B2);
    yb[PAD(o + 3 * s)] = cmul(w3, B3);
    yb[PAD(o + 4 * s)] = cmul(w4, B4);
    yb[PAD(o + 5 * s)] = cmul(w5, B5);
    yb[PAD(o + 6 * s)] = cmul(w6, B6);
    yb[PAD(o + 7 * s)] = cmul(w7, B7);
    float2* tp = xb; xb = yb; yb = tp;
  }
  // final radix-4 stage, s=512, twiddle-free (cb==0); 2 butterflies/thread
  __syncthreads();
#pragma unroll
  for (int ii = 0; ii < 2; ii++) {
    int i = tid + ii * TB;       // [0,512)
    float2 a0 = xb[PAD(i)], a1 = xb[PAD(i + 512)];
    float2 a2 = xb[PAD(i + 1024)], a3 = xb[PAD(i + 1536)];
    float2 S02 = cadd(a0, a2), D02 = csub(a0, a2);
    float2 S13 = cadd(a1, a3), D13 = csub(a1, a3);
    yb[PAD(i)]        = cadd(S02, S13);
    yb[PAD(i + 512)]  = cadd(D02, cmni(D13));
    yb[PAD(i + 1024)] = csub(S02, S13);
    yb[PAD(i + 1536)] = csub(D02, cmni(D13));
  }
  // buffers: A ->(s1) B ->(s8) A ->(s64) B ->(R4) A : spectrum in bufA
  __syncthreads();

  const float2* Z = bufA;
  u64* keys = (u64*)bufB;        // [0..1023]=row r0, [1024..2047]=row r0+1
  for (int i = tid; i < 1024; i += TB) {
    int kb = i + 1;
    float2 zk = Z[PAD(kb)];
    float2 zc = Z[PAD(2048 - kb)];
    float ax = zk.x + zc.x, ay = zk.y - zc.y;   // 2*X[kb]
    float bx = zk.x - zc.x, by = zk.y + zc.y;   // 2i*Y[kb]
    float m2a = ax * ax + ay * ay;              // 4*|X|^2 — const scale, order-safe
    float m2b = bx * bx + by * by;
    keys[i]        = ((u64)__float_as_uint(m2a) << 32) | (unsigned)(0xFFFFFFFFu - (unsigned)kb);
    keys[1024 + i] = ((u64)__float_as_uint(m2b) << 32) | (unsigned)(0xFFFFFFFFu - (unsigned)kb);
  }
  __syncthreads();   // all mag2 reads of bufA done -> safe to overwrite with rows

  // reload raw rows into dead bufA (both rows contiguous in seqs)
  float* srows = (float*)bufA;
  {
    const float4* s4 = (const float4*)row0;
    float4* r4 = (float4*)srows;
    for (int i = tid; i < 1024; i += TB) r4[i] = s4[i];   // 2*2048 floats
  }

  // top-6: waves 0-1 own row r0, waves 2-3 own row r0+1
  int rw2 = wv >> 1;
  u64* kb2 = keys + rw2 * 1024;
  int t2 = tid & 127;
  for (int r = 0; r < KP; r++) {
    u64 best = 0ull;
    for (int i = t2; i < 1024; i += 128) {
      u64 v = kb2[i];
      best = v > best ? v : best;
    }
    for (int off = 32; off > 0; off >>= 1) {
      u64 o = __shfl_down(best, off);
      best = o > best ? o : best;
    }
    if (lane == 0) wmax[wv] = best;
    __syncthreads();
    if (t2 == 0) {
      u64 b0 = wmax[rw2 * 2], b1 = wmax[rw2 * 2 + 1];
      best = b0 > b1 ? b0 : b1;
      int bin = (int)(0xFFFFFFFFu - (unsigned)(best & 0xFFFFFFFFull));
      if (bin < 1 || bin > 1024) bin = 1;
      kb2[bin - 1] = 0ull;
      int P = TLEN / bin;
      int cyc = TLEN / P;
      int base = TLEN - cyc * P;
      prm[rw2][r] = make_int4(P, base, cyc, 0);
    }
    __syncthreads();
  }
  // last __syncthreads covers: prm visible, srows loaded

  // fold: 12 (row,k) tasks over 4 waves (R4-verified per-wave fold)
  for (int task = wv; task < 2 * KP; task += 4) {
    int rw = task & 1, k = task >> 1;
    int4 pr = prm[rw][k];
    int P = pr.x, base = pr.y, cyc = pr.z;
    float inv = 1.0f / (float)cyc;
    const float* srow = srows + rw * TLEN;
    int row = r0 + rw, b = row >> 7, n = row & 127;
    float* dst = out + (size_t)(b * KP + k) * TLEN * NCH + n;

    if (P >= 64) {
      for (int p = lane; p < P; p += 64) {
        const float* sp = srow + base + p;
        float s = 0.f;
        for (int c = 0; c < cyc; c++) s += sp[c * P];
        dst[(size_t)p * NCH] = s * inv;
      }
    } else {
      int wc = 64 / P, u = wc * P, ci = lane / P;
      float v = 0.f;
      if (lane < u) {
        for (int c0 = 0; c0 < cyc; c0 += wc) {
          int c = c0 + ci;
          if (c < cyc) v += srow[base + c0 * P + lane];
        }
      }
      for (int s = P; s < u; s <<= 1) {
        float o = __shfl_down(v, s);
        if (lane + s < u) v += o;
      }
      if (lane < P) dst[(size_t)lane * NCH] = v * inv;
    }
  }
}

// ---------------------------------------------------------------------------
extern "C" void kernel_launch(void* const* d_in, const int* in_sizes, int n_in,
                              void* d_out, int out_size, void* d_ws, size_t ws_size,
                              hipStream_t stream) {
  const float* x = (const float*)d_in[0];
  float* out = (float*)d_out;
  float* seqs = (float*)d_ws;                    // 16.8 MB

  int n4 = out_size / 4;
  int fill_blocks = (n4 + 255) / 256;
  k_prep<<<1024 + fill_blocks, 256, 0, stream>>>(x, seqs, (float4*)out, n4);
  k_fft_fold<<<BN / 2, 256, 0, stream>>>(seqs, out);
}